// Round 5
// baseline (1122.074 us; speedup 1.0000x reference)
//
#include <hip/hip_runtime.h>
#include <math.h>

typedef __attribute__((ext_vector_type(8))) short short8;
typedef __attribute__((ext_vector_type(4))) float floatx4;
typedef __attribute__((ext_vector_type(2))) _Float16 half2v;
typedef unsigned short ush;

__device__ __forceinline__ ush f2bf(float f) {
    unsigned u = __builtin_bit_cast(unsigned, f);
    u += 0x7FFFu + ((u >> 16) & 1u);   // RNE
    return (ush)(u >> 16);
}

// ---------------------------------------------------------------------------
// Weights pre-converted ONCE per launch into bf16 tiles in the EXACT swizzled
// LDS image (R7). perm=1: stage-1 main k = r*4+ci (pad ci==3). perm=2 (R11):
// k = r*CIN + ci  <- src m*Ktot + ci*Kk + r, so NHWC convs get one tap r per
// 64-k step with contiguous channels.
// ---------------------------------------------------------------------------
#define NWT 10
struct PrepAll {
    const float* src[NWT];
    unsigned int dstOff[NWT];
    int M[NWT], Ktot[NWT], KT[NWT], Mblk[NWT], srcK[NWT], perm[NWT], cin[NWT];
    int startG[NWT + 1];
};

__global__ __launch_bounds__(256) void prep_all_k(PrepAll d, ush* __restrict__ P)
{
    const int t = blockIdx.x * 256 + threadIdx.x;
    if (t >= d.startG[NWT]) return;
    int wi = 0;
#pragma unroll
    for (int i = 1; i < NWT; ++i) wi += (t >= d.startG[i]);
    const int g8   = t - d.startG[wi];
    const int Mblk = d.Mblk[wi];
    const int ksC  = d.KT[wi] >> 6;
    const int g    = g8 & 7;
    int rest = g8 >> 3;
    const int row = rest % Mblk; rest /= Mblk;
    const int ks  = rest % ksC;
    const int mb  = rest / ksC;
    const int kchunk = g ^ (row & 7);
    const int gm  = mb * Mblk + row;
    const int M = d.M[wi], Ktot = d.Ktot[wi], srcK = d.srcK[wi];
    const int prm = d.perm[wi], cin = d.cin[wi];
    const float* __restrict__ src = d.src[wi];
    short8 v;
#pragma unroll
    for (int j = 0; j < 8; ++j) {
        int gk = ks * 64 + kchunk * 8 + j;
        bool ok = (gm < M) && (gk < Ktot);
        int gs = gk;
        if (prm == 1) { int ci = gk & 3, rr = gk >> 2; ok = ok && (ci < 3); gs = ci * 49 + rr; }
        if (prm == 2) { int ci = gk % cin, rr = gk / cin; gs = ci * (Ktot / cin) + rr; }
        float f = ok ? src[(size_t)gm * srcK + gs] : 0.f;
        v[j] = (short)f2bf(f);
    }
    *(short8*)(P + d.dstOff[wi] + (size_t)g8 * 8) = v;
}

// Implicit-GEMM conv on bf16 MFMA. MODE 0 zero-pad / 1 reflect / 2 deform.
// Tile BM=64*MT, BN=64, BK=64; 256 threads = 4 waves.
// R9: LDS meta once/block, scoped batched gathers. R10: NKS K-split partials.
// R11: LAYT=1 -> X is NHWC [HW][CIN], weights perm2 (k=r*CIN+ci): one 64-k
//      step = one tap r, contiguous channels -> corner loads are float4
//      (16 loads/kstep for deform, 4 for zero-pad, vs 64 scalar in NCHW).
//      ONHWC=1 (stage-1 main): epilogue LDS-transpose -> coalesced NHWC out.
template<int CIN,int KH,int KW,int STR,int PAD,int H,int W,int HO,int WO,
         int MODE,int MT,int PERM=0,int NKS=1,int LAYT=0,int ONHWC=0>
__global__ __launch_bounds__(256) void conv_mfma(
    const ush* __restrict__ Aprep,
    const float* __restrict__ X,      // NCHW [Z][CIN][H][W] or NHWC [Z][H*W][CIN]
    const float* __restrict__ OM,     // [Z][3*Kk][HO][WO] (deform only, NCHW)
    const float* __restrict__ bias,
    float* __restrict__ Out,          // [Z][M][HO*WO] (or NKS partials / NHWC)
    int M)
{
    constexpr int Kk   = KH*KW;
    constexpr int Ktot = PERM == 1 ? 4*Kk : CIN*Kk;
    constexpr int HWc  = H*W;
    constexpr int HOWO = HO*WO;
    constexpr int KT   = (Ktot + 63) & ~63;
    constexpr int KSC  = KT >> 6;
    constexpr int KSLICE = KT / NKS;
    constexpr bool KGUARD = (Ktot % 64 != 0);
    constexpr bool META2 = (MODE == 2) && (Kk == 16);              // deform meta LDS
    constexpr bool M2P   = (MODE == 2) && (PERM == 1);             // stage-1 deform
    constexpr bool M0R   = (MODE == 0) && (Kk == 16) && !LAYT;     // zero-pad reg idx
    constexpr bool MLUT  = (MODE == 1) || (MODE == 0 && Kk != 16)
                        || (MODE == 0 && Kk == 16 && LAYT);        // idx LDS table
    constexpr int KPAD = (Kk % 2 == 0) ? Kk + 1 : Kk;
    static_assert(KT % (64 * NKS) == 0, "");
    static_assert(PERM != 1 || (MODE == 2 && CIN == 3 && Kk == 49), "");
    static_assert(!LAYT || (CIN % 64 == 0 && Kk == 16), "");
    static_assert(!ONHWC || (MT == 1 && NKS == 1), "");

    const int z = blockIdx.z;
    const float* __restrict__ Xb  = X + (size_t)z * CIN * HWc;
    const float* __restrict__ OMb = (MODE == 2) ? (OM + (size_t)z * 3 * Kk * HOWO) : nullptr;

    const int mtiles = gridDim.y / NKS;
    const int my = (NKS > 1) ? ((int)blockIdx.y % mtiles) : blockIdx.y;
    const int ks = (NKS > 1) ? ((int)blockIdx.y / mtiles) : 0;

    float* __restrict__ Outb;
    if constexpr (NKS > 1) {
        const size_t PS = (size_t)gridDim.z * (size_t)M * HOWO;
        Outb = Out + (size_t)ks * PS + (size_t)z * (size_t)M * HOWO;
    } else {
        Outb = Out + (size_t)z * (size_t)M * HOWO;
    }

    const int n0   = blockIdx.x * 64;
    const int tid  = threadIdx.x;
    const int lane = tid & 63;
    const int wave = tid >> 6;
    const int quad = lane >> 4;
    const int l16  = lane & 15;

    const int bn2 = tid & 63;
    const int bkc = tid >> 6;
    const int gn2 = n0 + bn2;
    const int ho2 = gn2 / WO, wo2 = gn2 % WO;

    // ---- shared memory carve (Ts for ONHWC aliases As+Bs)
    constexpr int AB_BYTES = 64*MT*64*2 + 64*64*2;
    constexpr int TS_BYTES = ONHWC ? 64*64*4 : 0;
    constexpr int BASE_BYTES = AB_BYTES > TS_BYTES ? AB_BYTES : TS_BYTES;
    constexpr int MIB_OFF = BASE_BYTES;
    constexpr int MWH_OFF = MIB_OFF + (META2 ? 64*KPAD*4 : 0);
    constexpr int MI0_OFF = MWH_OFF + (META2 ? 64*KPAD*8 : 0);
    constexpr int SMEM_TOT = MI0_OFF + (MLUT ? 64*KPAD*4 : 0);
    __shared__ __align__(16) char smem[SMEM_TOT];
    ush (*As)[64] = reinterpret_cast<ush(*)[64]>(smem);
    ush (*Bs)[64] = reinterpret_cast<ush(*)[64]>(smem + 64*MT*64*2);
    int*   MIb = reinterpret_cast<int*>(smem + MIB_OFF);
    uint2* MWh = reinterpret_cast<uint2*>(smem + MWH_OFF);
    int*   MI0 = reinterpret_cast<int*>(smem + MI0_OFF);
    float* Ts  = reinterpret_cast<float*>(smem);

    // ---- one-time LDS meta (deform Kk==16). n = e&63 -> coalesced OM reads.
    if constexpr (META2) {
        for (int e = tid; e < 64 * Kk; e += 256) {
            int n = e & 63, r = e >> 6;
            int gn = n0 + n, ho = gn / WO, wo = gn % WO;
            int ky = r / KW, kx = r % KW;
            float offy = OMb[(size_t)(2 * r) * HOWO + gn];
            float offx = OMb[(size_t)(2 * r + 1) * HOWO + gn];
            float ml   = OMb[(size_t)(2 * Kk + r) * HOWO + gn];
            float mask = 1.f / (1.f + expf(-ml));
            float ys = (float)(ho * STR - PAD + ky) + offy;
            float xs = (float)(wo * STR - PAD + kx) + offx;
            float y0f = floorf(ys), x0f = floorf(xs);
            float dy = ys - y0f, dx = xs - x0f;
            int y0 = (int)y0f, x0 = (int)x0f;
            int yc0 = min(max(y0, 0), H - 1);
            int yc1 = min(max(y0 + 1, 0), H - 1);
            int xc0 = min(max(x0, 0), W - 1);
            int xc1 = min(max(x0 + 1, 0), W - 1);
            bool y0ok = (y0 >= 0) & (y0 < H), y1ok = (y0 + 1 >= 0) & (y0 + 1 < H);
            bool x0ok = (x0 >= 0) & (x0 < W), x1ok = (x0 + 1 >= 0) & (x0 + 1 < W);
            half2v w01, w23;
            w01[0] = (_Float16)((y0ok && x0ok) ? (1.f - dy) * (1.f - dx) * mask : 0.f);
            w01[1] = (_Float16)((y0ok && x1ok) ? (1.f - dy) * dx * mask : 0.f);
            w23[0] = (_Float16)((y1ok && x0ok) ? dy * (1.f - dx) * mask : 0.f);
            w23[1] = (_Float16)((y1ok && x1ok) ? dy * dx * mask : 0.f);
            MIb[n * KPAD + r] = (yc0 * W + xc0) | ((xc1 - xc0) << 24) | ((yc1 - yc0) << 25);
            MWh[n * KPAD + r] = make_uint2(__builtin_bit_cast(unsigned, w01),
                                           __builtin_bit_cast(unsigned, w23));
        }
        __syncthreads();
    }
    if constexpr (MLUT) {
        for (int e = tid; e < 64 * Kk; e += 256) {
            int n = e & 63, r = e >> 6;
            int gn = n0 + n, ho = gn / WO, wo = gn % WO;
            int ky = r / KW, kx = r % KW;
            int idx;
            if constexpr (MODE == 0) {
                int iy = ho * STR - PAD + ky;
                int ix = wo * STR - PAD + kx;
                idx = (iy >= 0 && iy < H && ix >= 0 && ix < W) ? iy * W + ix : -1;
            } else {
                int iy = ho - PAD + ky; iy = iy < 0 ? -iy : (iy >= H ? 2 * H - 2 - iy : iy);
                int ix = wo - PAD + kx; ix = ix < 0 ? -ix : (ix >= W ? 2 * W - 2 - ix : ix);
                idx = iy * W + ix;
            }
            MI0[n * KPAD + r] = idx;
        }
        __syncthreads();
    }

    int rix[M0R ? 16 : 1];
    if constexpr (M0R) {
#pragma unroll
        for (int j = 0; j < 16; ++j) {
            int ky = j / KW, kx = j % KW;
            int iy = ho2 * STR - PAD + ky;
            int ix = wo2 * STR - PAD + kx;
            rix[j] = (iy >= 0 && iy < H && ix >= 0 && ix < W) ? iy * W + ix : -1;
        }
    }

    floatx4 acc[MT][4];
#pragma unroll
    for (int s = 0; s < MT; ++s)
#pragma unroll
        for (int t = 0; t < 4; ++t) acc[s][t] = (floatx4){0.f, 0.f, 0.f, 0.f};

    for (int k0 = ks * KSLICE; k0 < ks * KSLICE + KSLICE; k0 += 64) {
        // ---- stage A: async DMA from pre-swizzled bf16 tiles (issued first)
        {
            const ush* At =
                Aprep + ((size_t)my * KSC + (k0 >> 6)) * (size_t)(64 * MT * 64);
#pragma unroll
            for (int c = 0; c < 2 * MT; ++c) {
                const int chunk = c * 4 + wave;
                __builtin_amdgcn_global_load_lds(
                    (const __attribute__((address_space(1))) void*)(At + (size_t)chunk * 512 + lane * 8),
                    (__attribute__((address_space(3))) void*)(&As[0][0] + chunk * 512),
                    16, 0, 0);
            }
        }

        // ---- stage B (sampled -> bf16 LDS), n-major
        {
            ush tmp[16];
            if constexpr (LAYT && MODE == 2) {
                // NHWC deform: one tap r, 16 contiguous channels per thread
                const int r   = k0 / CIN;                 // wave-uniform
                const int ci0 = (k0 % CIN) + bkc * 16;
                int packed = MIb[bn2 * KPAD + r];
                uint2 ww   = MWh[bn2 * KPAD + r];
                half2v w01 = __builtin_bit_cast(half2v, ww.x);
                half2v w23 = __builtin_bit_cast(half2v, ww.y);
                float W00 = (float)w01[0], W01 = (float)w01[1];
                float W10 = (float)w23[0], W11 = (float)w23[1];
                int base = packed & 0xFFFFFF;
                int dX = ((packed >> 24) & 1) ? CIN : 0;
                int dY = ((packed >> 25) & 1) ? W * CIN : 0;
                const float* p00 = Xb + (size_t)base * CIN + ci0;
#pragma unroll
                for (int qh = 0; qh < 2; ++qh) {
                    float4 a0[2], a1[2], a2[2], a3[2];
#pragma unroll
                    for (int q = 0; q < 2; ++q) {
                        int o = (qh * 2 + q) * 4;
                        a0[q] = *(const float4*)(p00 + o);
                        a1[q] = *(const float4*)(p00 + dX + o);
                        a2[q] = *(const float4*)(p00 + dY + o);
                        a3[q] = *(const float4*)(p00 + dY + dX + o);
                    }
#pragma unroll
                    for (int q = 0; q < 2; ++q) {
                        tmp[(qh*2+q)*4 + 0] = f2bf(W00*a0[q].x + W01*a1[q].x + W10*a2[q].x + W11*a3[q].x);
                        tmp[(qh*2+q)*4 + 1] = f2bf(W00*a0[q].y + W01*a1[q].y + W10*a2[q].y + W11*a3[q].y);
                        tmp[(qh*2+q)*4 + 2] = f2bf(W00*a0[q].z + W01*a1[q].z + W10*a2[q].z + W11*a3[q].z);
                        tmp[(qh*2+q)*4 + 3] = f2bf(W00*a0[q].w + W01*a1[q].w + W10*a2[q].w + W11*a3[q].w);
                    }
                }
            } else if constexpr (LAYT && MODE == 0) {
                // NHWC zero-pad: one tap r, 4 float4 loads
                const int r   = k0 / CIN;
                const int ci0 = (k0 % CIN) + bkc * 16;
                int idx = MI0[bn2 * KPAD + r];
                const float* p0 = Xb + (size_t)(idx < 0 ? 0 : idx) * CIN + ci0;
                float4 a[4];
#pragma unroll
                for (int q = 0; q < 4; ++q) a[q] = *(const float4*)(p0 + q * 4);
#pragma unroll
                for (int j = 0; j < 16; ++j) {
                    float v = (j & 3) == 0 ? a[j >> 2].x : (j & 3) == 1 ? a[j >> 2].y
                            : (j & 3) == 2 ? a[j >> 2].z : a[j >> 2].w;
                    tmp[j] = idx < 0 ? (ush)0 : f2bf(v);
                }
            } else if constexpr (META2) {
                // NCHW deform: meta from LDS in scoped 8-tap batches
                const int ci = (k0 >> 4) + bkc;
                const float* img = Xb + (size_t)ci * HWc;
                const int mb = bn2 * KPAD;
#pragma unroll
                for (int jh = 0; jh < 2; ++jh) {
                    int pk[8]; unsigned wa[8], wb[8];
#pragma unroll
                    for (int j = 0; j < 8; ++j) pk[j] = MIb[mb + jh * 8 + j];
#pragma unroll
                    for (int j = 0; j < 8; ++j) {
                        uint2 ww = MWh[mb + jh * 8 + j];
                        wa[j] = ww.x; wb[j] = ww.y;
                    }
                    float c0[8], c1[8], c2[8], c3[8];
#pragma unroll
                    for (int j = 0; j < 8; ++j) {
                        int p = pk[j];
                        int base = p & 0xFFFFFF;
                        int dxs  = (p >> 24) & 1;
                        int dys  = ((p >> 25) & 1) ? W : 0;
                        c0[j] = img[base];
                        c1[j] = img[base + dxs];
                        c2[j] = img[base + dys];
                        c3[j] = img[base + dys + dxs];
                    }
#pragma unroll
                    for (int j = 0; j < 8; ++j) {
                        half2v w01 = __builtin_bit_cast(half2v, wa[j]);
                        half2v w23 = __builtin_bit_cast(half2v, wb[j]);
                        tmp[jh * 8 + j] = f2bf((float)w01[0] * c0[j] + (float)w01[1] * c1[j]
                                             + (float)w23[0] * c2[j] + (float)w23[1] * c3[j]);
                    }
                }
            } else if constexpr (M2P) {
                // stage-1 deform, perm'd K: 4 slots share one r (3 planes + pad)
                const int kbase = k0 + bkc * 16;
                const int rbase = kbase >> 2;
#pragma unroll
                for (int u = 0; u < 4; ++u) {
                    const int r = rbase + u;
                    float v0 = 0.f, v1 = 0.f, v2 = 0.f;
                    if (r < Kk) {
                        const int ky = r / KW, kx = r - ky * KW;
                        float offy = OMb[(size_t)(2 * r) * HOWO + gn2];
                        float offx = OMb[(size_t)(2 * r + 1) * HOWO + gn2];
                        float ml   = OMb[(size_t)(2 * Kk + r) * HOWO + gn2];
                        float mask = 1.f / (1.f + expf(-ml));
                        float ys = (float)(ho2 * STR - PAD + ky) + offy;
                        float xs = (float)(wo2 * STR - PAD + kx) + offx;
                        float y0f = floorf(ys), x0f = floorf(xs);
                        float dy = ys - y0f, dx = xs - x0f;
                        int y0 = (int)y0f, x0 = (int)x0f;
                        int yc0 = min(max(y0, 0), H - 1);
                        int yc1 = min(max(y0 + 1, 0), H - 1);
                        int xc0 = min(max(x0, 0), W - 1);
                        int xc1 = min(max(x0 + 1, 0), W - 1);
                        bool y0ok = (y0 >= 0) & (y0 < H), y1ok = (y0 + 1 >= 0) & (y0 + 1 < H);
                        bool x0ok = (x0 >= 0) & (x0 < W), x1ok = (x0 + 1 >= 0) & (x0 + 1 < W);
                        float w00 = (y0ok && x0ok) ? (1.f - dy) * (1.f - dx) * mask : 0.f;
                        float w01 = (y0ok && x1ok) ? (1.f - dy) * dx * mask : 0.f;
                        float w10 = (y1ok && x0ok) ? dy * (1.f - dx) * mask : 0.f;
                        float w11 = (y1ok && x1ok) ? dy * dx * mask : 0.f;
                        int base = yc0 * W + xc0;
                        int dxs  = xc1 - xc0;
                        int dys  = (yc1 - yc0) ? W : 0;
                        float cc[12];
#pragma unroll
                        for (int ci = 0; ci < 3; ++ci) {
                            const float* img = Xb + (size_t)ci * HWc;
                            cc[ci * 4 + 0] = img[base];
                            cc[ci * 4 + 1] = img[base + dxs];
                            cc[ci * 4 + 2] = img[base + dys];
                            cc[ci * 4 + 3] = img[base + dys + dxs];
                        }
                        v0 = w00 * cc[0] + w01 * cc[1] + w10 * cc[2]  + w11 * cc[3];
                        v1 = w00 * cc[4] + w01 * cc[5] + w10 * cc[6]  + w11 * cc[7];
                        v2 = w00 * cc[8] + w01 * cc[9] + w10 * cc[10] + w11 * cc[11];
                    }
                    tmp[u * 4 + 0] = f2bf(v0);
                    tmp[u * 4 + 1] = f2bf(v1);
                    tmp[u * 4 + 2] = f2bf(v2);
                    tmp[u * 4 + 3] = 0;
                }
            } else if constexpr (M0R) {
                const int ci = (k0 >> 4) + bkc;
                const float* img = Xb + (size_t)ci * HWc;
                float raw[16];
#pragma unroll
                for (int j = 0; j < 16; ++j) raw[j] = img[rix[j] < 0 ? 0 : rix[j]];
#pragma unroll
                for (int j = 0; j < 16; ++j) tmp[j] = rix[j] < 0 ? (ush)0 : f2bf(raw[j]);
            } else {
                // NCHW MLUT: batched idx reads then unconditional clamped gathers
                int idxs[16], cis[16];
#pragma unroll
                for (int j = 0; j < 16; ++j) {
                    int gk = k0 + bkc * 16 + j;
                    int ci = (Kk == 16) ? (gk >> 4) : gk / Kk;
                    int r  = gk - ci * Kk;
                    int idx = MI0[bn2 * KPAD + r];
                    if (KGUARD && gk >= Ktot) idx = -1;
                    idxs[j] = idx; cis[j] = ci;
                }
                float raw[16];
#pragma unroll
                for (int j = 0; j < 16; ++j)
                    raw[j] = Xb[(size_t)cis[j] * HWc + (idxs[j] < 0 ? 0 : idxs[j])];
#pragma unroll
                for (int j = 0; j < 16; ++j)
                    tmp[j] = idxs[j] < 0 ? (ush)0 : f2bf(raw[j]);
            }
            short8 s0, s1;
#pragma unroll
            for (int j = 0; j < 8; ++j) { s0[j] = (short)tmp[j]; s1[j] = (short)tmp[8 + j]; }
            const int g0 = (bkc * 2)     ^ (bn2 & 7);
            const int g1 = (bkc * 2 + 1) ^ (bn2 & 7);
            *(short8*)&Bs[bn2][g0 * 8] = s0;
            *(short8*)&Bs[bn2][g1 * 8] = s1;
        }
        __syncthreads();

        // ---- MFMA: wave computes MT x 16(m) x 64(n), K=64
        {
            const int mrow = wave * 16 + l16;
#pragma unroll
            for (int kk = 0; kk < 2; ++kk) {
                const int kg = kk * 4 + quad;
                short8 a[MT];
#pragma unroll
                for (int s = 0; s < MT; ++s)
                    a[s] = *(const short8*)&As[s * 64 + mrow][((kg ^ (mrow & 7)) * 8)];
#pragma unroll
                for (int t = 0; t < 4; ++t) {
                    const int ncol = t * 16 + l16;
                    short8 b = *(const short8*)&Bs[ncol][((kg ^ (ncol & 7)) * 8)];
#pragma unroll
                    for (int s = 0; s < MT; ++s)
                        acc[s][t] = __builtin_amdgcn_mfma_f32_16x16x32_bf16(a[s], b, acc[s][t], 0, 0, 0);
                }
            }
        }
        __syncthreads();
    }

    // ---- epilogue
    if constexpr (ONHWC) {
        // LDS transpose -> coalesced NHWC store (M==64, full tile)
#pragma unroll
        for (int t = 0; t < 4; ++t) {
            int n = t * 16 + l16;
#pragma unroll
            for (int i = 0; i < 4; ++i) {
                int m = wave * 16 + quad * 4 + i;
                Ts[n * 64 + (m ^ ((n & 7) << 3))] = acc[0][t][i] + bias[m];
            }
        }
        __syncthreads();
        float* Outc = Out + ((size_t)z * HOWO + n0) * 64;
        for (int e = tid; e < 1024; e += 256) {
            int n = e >> 4, m4 = (e & 15) * 4;
            float4 v = *(float4*)&Ts[n * 64 + (m4 ^ ((n & 7) << 3))];
            *(float4*)(Outc + n * 64 + m4) = v;
        }
    } else {
#pragma unroll
        for (int s = 0; s < MT; ++s) {
#pragma unroll
            for (int t = 0; t < 4; ++t) {
                const int ng = n0 + t * 16 + l16;
#pragma unroll
                for (int i = 0; i < 4; ++i) {
                    int mg = my * (64 * MT) + s * 64 + wave * 16 + quad * 4 + i;
                    if (mg < M) {
                        float v = acc[s][t][i];
                        if constexpr (NKS == 1) v += bias[mg];
                        Outb[(size_t)mg * HOWO + ng] = v;
                    }
                }
            }
        }
    }
}

// Sum NP partial planes (stride PS) + bias -> out. One block per (z,m) row.
template<int NP>
__global__ __launch_bounds__(256) void reduce_bias_k(
    const float* __restrict__ P, size_t PS, const float* __restrict__ bias,
    float* __restrict__ out, int M, int HOWO)
{
    const int bc = blockIdx.x;
    const int m  = bc % M;
    const float b = bias[m];
    const size_t off = (size_t)bc * HOWO;
    for (int i = threadIdx.x * 4; i < HOWO; i += 1024) {
        float4 a = *(const float4*)(P + off + i);
#pragma unroll
        for (int p = 1; p < NP; ++p) {
            float4 c = *(const float4*)(P + (size_t)p * PS + off + i);
            a.x += c.x; a.y += c.y; a.z += c.z; a.w += c.w;
        }
        a.x += b; a.y += b; a.z += b; a.w += b;
        *(float4*)(out + off + i) = a;
    }
}

// NCHW instance norm (per (b,c) over HW); optional ReLU/dual/add-in. float4.
template<bool RELU, bool DUAL, bool ADDIN>
__global__ __launch_bounds__(256) void instnorm_k(
    const float* __restrict__ in, float* __restrict__ out,
    float* __restrict__ out2, int HW)
{
    const int bc = blockIdx.x;
    const float4* p4 = (const float4*)(in + (size_t)bc * HW);
    const int n4 = HW >> 2;
    float s = 0.f, ss = 0.f;
    for (int i = threadIdx.x; i < n4; i += 256) {
        float4 v = p4[i];
        s  += v.x + v.y + v.z + v.w;
        ss += v.x * v.x + v.y * v.y + v.z * v.z + v.w * v.w;
    }
    __shared__ float rs[256], rq[256];
    rs[threadIdx.x] = s; rq[threadIdx.x] = ss;
    __syncthreads();
    for (int o = 128; o > 0; o >>= 1) {
        if (threadIdx.x < o) { rs[threadIdx.x] += rs[threadIdx.x + o]; rq[threadIdx.x] += rq[threadIdx.x + o]; }
        __syncthreads();
    }
    float mean = rs[0] / (float)HW;
    float var  = rq[0] / (float)HW - mean * mean;
    float inv  = rsqrtf(var + 1e-5f);
    float4* q4  = (float4*)(out + (size_t)bc * HW);
    float4* q24 = DUAL ? (float4*)(out2 + (size_t)bc * HW) : nullptr;
    for (int i = threadIdx.x; i < n4; i += 256) {
        float4 v = p4[i];
        v.x = (v.x - mean) * inv; v.y = (v.y - mean) * inv;
        v.z = (v.z - mean) * inv; v.w = (v.w - mean) * inv;
        if (RELU) {
            v.x = fmaxf(v.x, 0.f); v.y = fmaxf(v.y, 0.f);
            v.z = fmaxf(v.z, 0.f); v.w = fmaxf(v.w, 0.f);
        }
        if (ADDIN) {
            float4 o = q4[i];
            o.x += v.x; o.y += v.y; o.z += v.z; o.w += v.w;
            q4[i] = o;
        } else {
            q4[i] = v;
            if (DUAL) q24[i] = v;
        }
    }
}

// NHWC instance-norm stats: per (z, chunk of 1024 hw) partial s/ss per channel.
// X: [Z][HW][64]. P: [Z][16][64] float2 (s,ss). Fully coalesced.
__global__ __launch_bounds__(256) void in_stats_nhwc(
    const float* __restrict__ X, float2* __restrict__ P, int HW)
{
    const int z = blockIdx.x, chunk = blockIdx.y;
    const int tid = threadIdx.x;
    const int cg = tid & 15, seg = tid >> 4;       // c0 = cg*4, 16 hw-segs
    const int c0 = cg * 4;
    float4 s4 = make_float4(0.f, 0.f, 0.f, 0.f);
    float4 q4 = make_float4(0.f, 0.f, 0.f, 0.f);
    const float* base = X + ((size_t)z * HW + chunk * 1024) * 64;
    for (int hw = seg; hw < 1024; hw += 16) {
        float4 v = *(const float4*)(base + (size_t)hw * 64 + c0);
        s4.x += v.x; s4.y += v.y; s4.z += v.z; s4.w += v.w;
        q4.x += v.x * v.x; q4.y += v.y * v.y; q4.z += v.z * v.z; q4.w += v.w * v.w;
    }
    __shared__ float4 rs[256], rq[256];
    rs[tid] = s4; rq[tid] = q4;
    __syncthreads();
    if (tid < 16) {
        float4 S = rs[tid], Q = rq[tid];
        for (int g = 1; g < 16; ++g) {
            float4 a = rs[g * 16 + tid], b = rq[g * 16 + tid];
            S.x += a.x; S.y += a.y; S.z += a.z; S.w += a.w;
            Q.x += b.x; Q.y += b.y; Q.z += b.z; Q.w += b.w;
        }
        float2* po = P + ((size_t)z * 16 + chunk) * 64 + tid * 4;
        po[0] = make_float2(S.x, Q.x);
        po[1] = make_float2(S.y, Q.y);
        po[2] = make_float2(S.z, Q.z);
        po[3] = make_float2(S.w, Q.w);
    }
}

// NHWC normalize + ReLU in place. grid (Z, 64 chunks of 256 hw).
__global__ __launch_bounds__(256) void in_norm_nhwc(
    const float2* __restrict__ P, float* __restrict__ X, int HW)
{
    const int z = blockIdx.x, chunk = blockIdx.y;
    const int tid = threadIdx.x;
    __shared__ float2 mi[64];
    if (tid < 64) {
        float s = 0.f, q = 0.f;
        for (int g = 0; g < 16; ++g) {
            float2 p = P[((size_t)z * 16 + g) * 64 + tid];
            s += p.x; q += p.y;
        }
        float mean = s / (float)HW;
        float var  = q / (float)HW - mean * mean;
        mi[tid] = make_float2(mean, rsqrtf(var + 1e-5f));
    }
    __syncthreads();
    float* base = X + ((size_t)z * HW + chunk * 256) * 64;
    for (int e = tid; e < 4096; e += 256) {
        int c0 = (e & 15) * 4;
        float4 v = *(float4*)(base + (size_t)e * 4);
        float2 m0 = mi[c0], m1 = mi[c0 + 1], m2 = mi[c0 + 2], m3 = mi[c0 + 3];
        v.x = fmaxf((v.x - m0.x) * m0.y, 0.f);
        v.y = fmaxf((v.y - m1.x) * m1.y, 0.f);
        v.z = fmaxf((v.z - m2.x) * m2.y, 0.f);
        v.w = fmaxf((v.w - m3.x) * m3.y, 0.f);
        *(float4*)(base + (size_t)e * 4) = v;
    }
}

// Tiled NCHW [Z][C][HW] -> NHWC [Z][HW][C] transpose. grid (HW/64, C/64, Z).
__global__ __launch_bounds__(256) void transpose_chw_hwc(
    const float* __restrict__ src, float* __restrict__ dst, int C, int HW)
{
    __shared__ float T[64][65];
    const int z = blockIdx.z, cb = blockIdx.y * 64, hb = blockIdx.x * 64;
    const int tid = threadIdx.x;
    for (int e = tid; e < 1024; e += 256) {
        int c = e >> 4, h4 = (e & 15) * 4;
        float4 v = *(const float4*)(src + ((size_t)z * C + cb + c) * HW + hb + h4);
        T[c][h4] = v.x; T[c][h4 + 1] = v.y; T[c][h4 + 2] = v.z; T[c][h4 + 3] = v.w;
    }
    __syncthreads();
    for (int e = tid; e < 1024; e += 256) {
        int h = e >> 4, c4 = (e & 15) * 4;
        float4 v = make_float4(T[c4][h], T[c4 + 1][h], T[c4 + 2][h], T[c4 + 3][h]);
        *(float4*)(dst + ((size_t)z * HW + hb + h) * C + cb + c4) = v;
    }
}

extern "C" void kernel_launch(void* const* d_in, const int* in_sizes, int n_in,
                              void* d_out, int out_size, void* d_ws, size_t ws_size,
                              hipStream_t stream)
{
    const float* x      = (const float*)d_in[0];
    const float* w_off1 = (const float*)d_in[1];
    const float* b_off1 = (const float*)d_in[2];
    const float* w1     = (const float*)d_in[3];
    const float* b1     = (const float*)d_in[4];
    const float* w_off2 = (const float*)d_in[5];
    const float* b_off2 = (const float*)d_in[6];
    const float* w2     = (const float*)d_in[7];
    const float* b2     = (const float*)d_in[8];
    const float* w_off3 = (const float*)d_in[9];
    const float* b_off3 = (const float*)d_in[10];
    const float* w3     = (const float*)d_in[11];
    const float* b3     = (const float*)d_in[12];
    const float* rwa[2] = {(const float*)d_in[13], (const float*)d_in[17]};
    const float* rba[2] = {(const float*)d_in[14], (const float*)d_in[18]};
    const float* rwb[2] = {(const float*)d_in[15], (const float*)d_in[19]};
    const float* rbb[2] = {(const float*)d_in[16], (const float*)d_in[20]};

    float* out   = (float*)d_out;
    float* h_out = out;                         // [16,256,32,32]
    float* skip2 = out + 4194304;               // [16,128,64,64]
    float* skip3 = out + 4194304 + 8388608;     // [16,256,32,32]

    // workspace (floats), time-multiplexed:
    //  h1 region [0..16.77M): h1 NHWC (stages 1-2) -> skip2t NHWC [0..8.39M)
    //    + kp partials [8.39M..16.77M) (stage 3 & residuals)
    //  pool: om1 [0..9.63M) | om2 [0..3.15M) | om3 [3.15M..3.93M)
    //        y1 [0..4.19M) | y2 [4.19M..8.39M)
    //        wprep [9.63M..11.27M) | Pst [11.27M..11.31M)
    float* wsf    = (float*)d_ws;
    float* h1     = wsf;                    // NHWC [16][16384][64]
    float* pool   = h1 + 16777216;
    float* om1    = pool;
    float* om2    = pool;
    float* om3    = pool + 3145728;
    float* y1     = pool;
    float* y2     = pool + 4194304;
    float* skip2t = h1;                     // NHWC [16][4096][128]
    float* kp     = h1 + 8388608;
    ush*   wprep  = (ush*)(pool + 9633792);
    float2* Pst   = (float2*)(pool + 11272192);   // [16][16][64]

    // ---- Weight prep
    {
        PrepAll pd;
        const float* srcs[NWT] = {w_off1, w1, w_off2, w2, w_off3, w3,
                                  rwa[0], rwb[0], rwa[1], rwb[1]};
        const int Ms  [NWT] = {147, 64, 48, 128, 48, 256, 256, 256, 256, 256};
        const int Kts [NWT] = {147, 196, 1024, 1024, 2048, 2048, 2304, 2304, 2304, 2304};
        const int KTs [NWT] = {192, 256, 1024, 1024, 2048, 2048, 2304, 2304, 2304, 2304};
        const int Mbs [NWT] = {128, 64, 64, 128, 64, 128, 128, 128, 128, 128};
        const int sKs [NWT] = {147, 147, 1024, 1024, 2048, 2048, 2304, 2304, 2304, 2304};
        const int prm [NWT] = {0, 1, 2, 2, 2, 2, 0, 0, 0, 0};
        const int cns [NWT] = {3, 3, 64, 64, 128, 128, 256, 256, 256, 256};
        int sg = 0;
        pd.startG[0] = 0;
        for (int i = 0; i < NWT; ++i) {
            pd.src[i] = srcs[i];
            pd.M[i] = Ms[i]; pd.Ktot[i] = Kts[i]; pd.KT[i] = KTs[i];
            pd.Mblk[i] = Mbs[i]; pd.srcK[i] = sKs[i]; pd.perm[i] = prm[i];
            pd.cin[i] = cns[i];
            pd.dstOff[i] = (unsigned)sg * 8u;
            int mb = (Ms[i] + Mbs[i] - 1) / Mbs[i];
            sg += mb * (KTs[i] >> 6) * Mbs[i] * 8;
            pd.startG[i + 1] = sg;
        }
        prep_all_k<<<dim3((sg + 255) / 256), 256, 0, stream>>>(pd, wprep);
    }
    const ush* pw_off1 = wprep + 0;
    const ush* pw1     = wprep + 49152;
    const ush* pw_off2 = wprep + 65536;
    const ush* pw2     = wprep + 131072;
    const ush* pw_off3 = wprep + 262144;
    const ush* pw3     = wprep + 393216;
    const ush* prwa[2] = {wprep + 917504,  wprep + 2097152};
    const ush* prwb[2] = {wprep + 1507328, wprep + 2686976};

    // ---- Stage 1: 7x7 s1 p3, 3 -> 64ch @128x128; h1 written NHWC
    for (int c = 0; c < 4; ++c) {
        const float* xc = x + (size_t)c * 4 * 3 * 16384;
        conv_mfma<3,7,7,1,3,128,128,128,128,0,2><<<dim3(256, 2, 4), 256, 0, stream>>>(
            pw_off1, xc, nullptr, b_off1, om1, 147);
        conv_mfma<3,7,7,1,3,128,128,128,128,2,1,1,1,0,1><<<dim3(256, 1, 4), 256, 0, stream>>>(
            pw1, xc, om1, b1, h1 + (size_t)c * 4 * 16384 * 64, 64);
    }
    in_stats_nhwc<<<dim3(16, 16), 256, 0, stream>>>(h1, Pst, 16384);
    in_norm_nhwc<<<dim3(16, 64), 256, 0, stream>>>(Pst, h1, 16384);

    // ---- Stage 2: 4x4 s2 p1, 64 -> 128ch @64x64 (NHWC input)
    conv_mfma<64,4,4,2,1,128,128,64,64,0,1,0,1,1><<<dim3(64, 1, 16), 256, 0, stream>>>(
        pw_off2, h1, nullptr, b_off2, om2, 48);
    conv_mfma<64,4,4,2,1,128,128,64,64,2,2,0,1,1><<<dim3(64, 1, 16), 256, 0, stream>>>(
        pw2, h1, om2, b2, skip2, 128);
    instnorm_k<true,false,false><<<16 * 128, 256, 0, stream>>>(skip2, skip2, nullptr, 4096);
    transpose_chw_hwc<<<dim3(64, 2, 16), 256, 0, stream>>>(skip2, skip2t, 128, 4096);

    // ---- Stage 3: 4x4 s2 p1, 128 -> 256ch @32x32 (NHWC input, K-split)
    conv_mfma<128,4,4,2,1,64,64,32,32,0,1,0,4,1><<<dim3(16, 4, 16), 256, 0, stream>>>(
        pw_off3, skip2t, nullptr, b_off3, kp, 48);
    reduce_bias_k<4><<<16 * 48, 256, 0, stream>>>(kp, 786432, b_off3, om3, 48, 1024);
    conv_mfma<128,4,4,2,1,64,64,32,32,2,2,0,2,1><<<dim3(16, 4, 16), 256, 0, stream>>>(
        pw3, skip2t, om3, b3, kp, 256);
    reduce_bias_k<2><<<16 * 256, 256, 0, stream>>>(kp, 4194304, b3, skip3, 256, 1024);
    instnorm_k<true,true,false><<<16 * 256, 256, 0, stream>>>(skip3, skip3, h_out, 1024);

    // ---- Residual blocks: reflect 3x3, 256ch @32x32 (NCHW, K-split 2)
    for (int r = 0; r < 2; ++r) {
        conv_mfma<256,3,3,1,1,32,32,32,32,1,2,0,2><<<dim3(16, 4, 16), 256, 0, stream>>>(
            prwa[r], h_out, nullptr, rba[r], kp, 256);
        reduce_bias_k<2><<<16 * 256, 256, 0, stream>>>(kp, 4194304, rba[r], y1, 256, 1024);
        instnorm_k<true,false,false><<<16 * 256, 256, 0, stream>>>(y1, y1, nullptr, 1024);
        conv_mfma<256,3,3,1,1,32,32,32,32,1,2,0,2><<<dim3(16, 4, 16), 256, 0, stream>>>(
            prwb[r], y1, nullptr, rbb[r], kp, 256);
        reduce_bias_k<2><<<16 * 256, 256, 0, stream>>>(kp, 4194304, rbb[r], y2, 256, 1024);
        instnorm_k<false,false,true><<<16 * 256, 256, 0, stream>>>(y2, h_out, nullptr, 1024);
    }
}

// Round 6
// 938.391 us; speedup vs baseline: 1.1957x; 1.1957x over previous
//
#include <hip/hip_runtime.h>
#include <math.h>

typedef __attribute__((ext_vector_type(8))) short short8;
typedef __attribute__((ext_vector_type(16))) short short16;
typedef __attribute__((ext_vector_type(4))) short sh4;
typedef __attribute__((ext_vector_type(4))) float floatx4;
typedef __attribute__((ext_vector_type(2))) _Float16 half2v;
typedef unsigned short ush;

__device__ __forceinline__ ush f2bf(float f) {
    unsigned u = __builtin_bit_cast(unsigned, f);
    u += 0x7FFFu + ((u >> 16) & 1u);   // RNE
    return (ush)(u >> 16);
}
__device__ __forceinline__ float bf2f(short s) {
    return __builtin_bit_cast(float, ((unsigned)(ush)s) << 16);
}

// ---------------------------------------------------------------------------
// Weights pre-converted ONCE per launch into bf16 tiles in the EXACT swizzled
// LDS image (R7). perm=1: stage-1 main k = r*4+ci (pad ci==3). perm=2:
// k = r*CIN + ci (NHWC convs: one tap r per 64-k step, contiguous channels).
// ---------------------------------------------------------------------------
#define NWT 10
struct PrepAll {
    const float* src[NWT];
    unsigned int dstOff[NWT];
    int M[NWT], Ktot[NWT], KT[NWT], Mblk[NWT], srcK[NWT], perm[NWT], cin[NWT];
    int startG[NWT + 1];
};

__global__ __launch_bounds__(256) void prep_all_k(PrepAll d, ush* __restrict__ P)
{
    const int t = blockIdx.x * 256 + threadIdx.x;
    if (t >= d.startG[NWT]) return;
    int wi = 0;
#pragma unroll
    for (int i = 1; i < NWT; ++i) wi += (t >= d.startG[i]);
    const int g8   = t - d.startG[wi];
    const int Mblk = d.Mblk[wi];
    const int ksC  = d.KT[wi] >> 6;
    const int g    = g8 & 7;
    int rest = g8 >> 3;
    const int row = rest % Mblk; rest /= Mblk;
    const int ks  = rest % ksC;
    const int mb  = rest / ksC;
    const int kchunk = g ^ (row & 7);
    const int gm  = mb * Mblk + row;
    const int M = d.M[wi], Ktot = d.Ktot[wi], srcK = d.srcK[wi];
    const int prm = d.perm[wi], cin = d.cin[wi];
    const float* __restrict__ src = d.src[wi];
    short8 v;
#pragma unroll
    for (int j = 0; j < 8; ++j) {
        int gk = ks * 64 + kchunk * 8 + j;
        bool ok = (gm < M) && (gk < Ktot);
        int gs = gk;
        if (prm == 1) { int ci = gk & 3, rr = gk >> 2; ok = ok && (ci < 3); gs = ci * 49 + rr; }
        if (prm == 2) { int ci = gk % cin, rr = gk / cin; gs = ci * (Ktot / cin) + rr; }
        float f = ok ? src[(size_t)gm * srcK + gs] : 0.f;
        v[j] = (short)f2bf(f);
    }
    *(short8*)(P + d.dstOff[wi] + (size_t)g8 * 8) = v;
}

// Implicit-GEMM conv on bf16 MFMA. MODE 0 zero-pad / 1 reflect / 2 deform.
// Tile BM=64*MT, BN=64, BK=64; 256 threads = 4 waves.
// R9: LDS meta once/block + batched gathers. R10: NKS K-split partials.
// R11: LAYT=1 -> X is NHWC, weights perm2. R12: LAYT inputs are bf16
// (one dwordx4 = 16ch per corner; zero-pad path is a direct bf16 copy) and
// ZSWZ=1 remaps blocks so each XCD owns gz/8 consecutive z's (L2-resident
// input; FETCH was 3.4x amplified by NHWC pixel-record scatter).
template<int CIN,int KH,int KW,int STR,int PAD,int H,int W,int HO,int WO,
         int MODE,int MT,int PERM=0,int NKS=1,int LAYT=0,int ONHWC=0,int ZSWZ=0>
__global__ __launch_bounds__(256) void conv_mfma(
    const ush* __restrict__ Aprep,
    const float* __restrict__ X,      // NCHW fp32, or NHWC bf16 when LAYT
    const float* __restrict__ OM,     // [Z][3*Kk][HO][WO] (deform only)
    const float* __restrict__ bias,
    float* __restrict__ Out,          // [Z][M][HO*WO] (or NKS partials / NHWC)
    int M)
{
    constexpr int Kk   = KH*KW;
    constexpr int Ktot = PERM == 1 ? 4*Kk : CIN*Kk;
    constexpr int HWc  = H*W;
    constexpr int HOWO = HO*WO;
    constexpr int KT   = (Ktot + 63) & ~63;
    constexpr int KSC  = KT >> 6;
    constexpr int KSLICE = KT / NKS;
    constexpr bool KGUARD = (Ktot % 64 != 0);
    constexpr bool META2 = (MODE == 2) && (Kk == 16);
    constexpr bool M2P   = (MODE == 2) && (PERM == 1);
    constexpr bool M0R   = (MODE == 0) && (Kk == 16) && !LAYT;
    constexpr bool MLUT  = (MODE == 1) || (MODE == 0 && Kk != 16)
                        || (MODE == 0 && Kk == 16 && LAYT);
    constexpr int KPAD = (Kk % 2 == 0) ? Kk + 1 : Kk;
    static_assert(KT % (64 * NKS) == 0, "");
    static_assert(PERM != 1 || (MODE == 2 && CIN == 3 && Kk == 49), "");
    static_assert(!LAYT || (CIN % 64 == 0 && Kk == 16), "");
    static_assert(!ONHWC || (MT == 1 && NKS == 1), "");

    // ---- optional XCD-locality remap (bijective; needs gz%8==0, total%8==0)
    int bx = blockIdx.x, by = blockIdx.y, bz = blockIdx.z;
    if constexpr (ZSWZ) {
        const int gx = gridDim.x, gy = gridDim.y, gz = gridDim.z;
        const int gxy = gx * gy;
        int flat = bx + gx * (by + gy * bz);
        int xcd = flat & 7, rank = flat >> 3;
        int zloc = rank / gxy, rem = rank - zloc * gxy;
        bz = xcd * (gz >> 3) + zloc;
        by = rem / gx; bx = rem - (rem / gx) * gx;
    }

    const int z = bz;
    const float* __restrict__ Xb  = LAYT ? nullptr : (X + (size_t)z * CIN * HWc);
    const ush*   __restrict__ Xh  = LAYT ? ((const ush*)X + (size_t)z * CIN * HWc) : nullptr;
    const float* __restrict__ OMb = (MODE == 2) ? (OM + (size_t)z * 3 * Kk * HOWO) : nullptr;

    const int mtiles = gridDim.y / NKS;
    const int my = (NKS > 1) ? (by % mtiles) : by;
    const int ks = (NKS > 1) ? (by / mtiles) : 0;

    float* __restrict__ Outb;
    if constexpr (NKS > 1) {
        const size_t PS = (size_t)gridDim.z * (size_t)M * HOWO;
        Outb = Out + (size_t)ks * PS + (size_t)z * (size_t)M * HOWO;
    } else {
        Outb = Out + (size_t)z * (size_t)M * HOWO;
    }

    const int n0   = bx * 64;
    const int tid  = threadIdx.x;
    const int lane = tid & 63;
    const int wave = tid >> 6;
    const int quad = lane >> 4;
    const int l16  = lane & 15;

    const int bn2 = tid & 63;
    const int bkc = tid >> 6;
    const int gn2 = n0 + bn2;
    const int ho2 = gn2 / WO, wo2 = gn2 % WO;

    // ---- shared memory carve (Ts for ONHWC aliases As+Bs)
    constexpr int AB_BYTES = 64*MT*64*2 + 64*64*2;
    constexpr int TS_BYTES = ONHWC ? 64*64*4 : 0;
    constexpr int BASE_BYTES = AB_BYTES > TS_BYTES ? AB_BYTES : TS_BYTES;
    constexpr int MIB_OFF = BASE_BYTES;
    constexpr int MWH_OFF = MIB_OFF + (META2 ? 64*KPAD*4 : 0);
    constexpr int MI0_OFF = MWH_OFF + (META2 ? 64*KPAD*8 : 0);
    constexpr int SMEM_TOT = MI0_OFF + (MLUT ? 64*KPAD*4 : 0);
    __shared__ __align__(16) char smem[SMEM_TOT];
    ush (*As)[64] = reinterpret_cast<ush(*)[64]>(smem);
    ush (*Bs)[64] = reinterpret_cast<ush(*)[64]>(smem + 64*MT*64*2);
    int*   MIb = reinterpret_cast<int*>(smem + MIB_OFF);
    uint2* MWh = reinterpret_cast<uint2*>(smem + MWH_OFF);
    int*   MI0 = reinterpret_cast<int*>(smem + MI0_OFF);
    float* Ts  = reinterpret_cast<float*>(smem);

    // ---- one-time LDS meta (deform Kk==16). n = e&63 -> coalesced OM reads.
    if constexpr (META2) {
        for (int e = tid; e < 64 * Kk; e += 256) {
            int n = e & 63, r = e >> 6;
            int gn = n0 + n, ho = gn / WO, wo = gn % WO;
            int ky = r / KW, kx = r % KW;
            float offy = OMb[(size_t)(2 * r) * HOWO + gn];
            float offx = OMb[(size_t)(2 * r + 1) * HOWO + gn];
            float ml   = OMb[(size_t)(2 * Kk + r) * HOWO + gn];
            float mask = 1.f / (1.f + expf(-ml));
            float ys = (float)(ho * STR - PAD + ky) + offy;
            float xs = (float)(wo * STR - PAD + kx) + offx;
            float y0f = floorf(ys), x0f = floorf(xs);
            float dy = ys - y0f, dx = xs - x0f;
            int y0 = (int)y0f, x0 = (int)x0f;
            int yc0 = min(max(y0, 0), H - 1);
            int yc1 = min(max(y0 + 1, 0), H - 1);
            int xc0 = min(max(x0, 0), W - 1);
            int xc1 = min(max(x0 + 1, 0), W - 1);
            bool y0ok = (y0 >= 0) & (y0 < H), y1ok = (y0 + 1 >= 0) & (y0 + 1 < H);
            bool x0ok = (x0 >= 0) & (x0 < W), x1ok = (x0 + 1 >= 0) & (x0 + 1 < W);
            half2v w01, w23;
            w01[0] = (_Float16)((y0ok && x0ok) ? (1.f - dy) * (1.f - dx) * mask : 0.f);
            w01[1] = (_Float16)((y0ok && x1ok) ? (1.f - dy) * dx * mask : 0.f);
            w23[0] = (_Float16)((y1ok && x0ok) ? dy * (1.f - dx) * mask : 0.f);
            w23[1] = (_Float16)((y1ok && x1ok) ? dy * dx * mask : 0.f);
            MIb[n * KPAD + r] = (yc0 * W + xc0) | ((xc1 - xc0) << 24) | ((yc1 - yc0) << 25);
            MWh[n * KPAD + r] = make_uint2(__builtin_bit_cast(unsigned, w01),
                                           __builtin_bit_cast(unsigned, w23));
        }
        __syncthreads();
    }
    if constexpr (MLUT) {
        for (int e = tid; e < 64 * Kk; e += 256) {
            int n = e & 63, r = e >> 6;
            int gn = n0 + n, ho = gn / WO, wo = gn % WO;
            int ky = r / KW, kx = r % KW;
            int idx;
            if constexpr (MODE == 0) {
                int iy = ho * STR - PAD + ky;
                int ix = wo * STR - PAD + kx;
                idx = (iy >= 0 && iy < H && ix >= 0 && ix < W) ? iy * W + ix : -1;
            } else {
                int iy = ho - PAD + ky; iy = iy < 0 ? -iy : (iy >= H ? 2 * H - 2 - iy : iy);
                int ix = wo - PAD + kx; ix = ix < 0 ? -ix : (ix >= W ? 2 * W - 2 - ix : ix);
                idx = iy * W + ix;
            }
            MI0[n * KPAD + r] = idx;
        }
        __syncthreads();
    }

    int rix[M0R ? 16 : 1];
    if constexpr (M0R) {
#pragma unroll
        for (int j = 0; j < 16; ++j) {
            int ky = j / KW, kx = j % KW;
            int iy = ho2 * STR - PAD + ky;
            int ix = wo2 * STR - PAD + kx;
            rix[j] = (iy >= 0 && iy < H && ix >= 0 && ix < W) ? iy * W + ix : -1;
        }
    }

    floatx4 acc[MT][4];
#pragma unroll
    for (int s = 0; s < MT; ++s)
#pragma unroll
        for (int t = 0; t < 4; ++t) acc[s][t] = (floatx4){0.f, 0.f, 0.f, 0.f};

    for (int k0 = ks * KSLICE; k0 < ks * KSLICE + KSLICE; k0 += 64) {
        // ---- stage A: async DMA from pre-swizzled bf16 tiles (issued first)
        {
            const ush* At =
                Aprep + ((size_t)my * KSC + (k0 >> 6)) * (size_t)(64 * MT * 64);
#pragma unroll
            for (int c = 0; c < 2 * MT; ++c) {
                const int chunk = c * 4 + wave;
                __builtin_amdgcn_global_load_lds(
                    (const __attribute__((address_space(1))) void*)(At + (size_t)chunk * 512 + lane * 8),
                    (__attribute__((address_space(3))) void*)(&As[0][0] + chunk * 512),
                    16, 0, 0);
            }
        }

        // ---- stage B (sampled -> bf16 LDS), n-major
        {
            short8 s0, s1;
            if constexpr (LAYT && MODE == 0) {
                // NHWC bf16 zero-pad: direct copy, one dwordx4
                const int r   = k0 / CIN;
                const int ci0 = (k0 % CIN) + bkc * 16;
                int idx = MI0[bn2 * KPAD + r];
                const ush* p0 = Xh + (size_t)(idx < 0 ? 0 : idx) * CIN + ci0;
                short16 v = *(const short16*)p0;
#pragma unroll
                for (int j = 0; j < 8; ++j) { s0[j] = v[j]; s1[j] = v[8 + j]; }
                if (idx < 0) {
#pragma unroll
                    for (int j = 0; j < 8; ++j) { s0[j] = 0; s1[j] = 0; }
                }
            } else {
                ush tmp[16];
                if constexpr (LAYT && MODE == 2) {
                    // NHWC bf16 deform: one tap r, 4 corner dwordx4 loads
                    const int r   = k0 / CIN;
                    const int ci0 = (k0 % CIN) + bkc * 16;
                    int packed = MIb[bn2 * KPAD + r];
                    uint2 ww   = MWh[bn2 * KPAD + r];
                    half2v w01 = __builtin_bit_cast(half2v, ww.x);
                    half2v w23 = __builtin_bit_cast(half2v, ww.y);
                    float W00 = (float)w01[0], W01 = (float)w01[1];
                    float W10 = (float)w23[0], W11 = (float)w23[1];
                    int base = packed & 0xFFFFFF;
                    int dX = ((packed >> 24) & 1) ? CIN : 0;
                    int dY = ((packed >> 25) & 1) ? W * CIN : 0;
                    const ush* p00 = Xh + (size_t)base * CIN + ci0;
                    short16 b0 = *(const short16*)(p00);
                    short16 b1 = *(const short16*)(p00 + dX);
                    short16 b2 = *(const short16*)(p00 + dY);
                    short16 b3 = *(const short16*)(p00 + dY + dX);
#pragma unroll
                    for (int j = 0; j < 16; ++j) {
                        tmp[j] = f2bf(W00 * bf2f(b0[j]) + W01 * bf2f(b1[j])
                                    + W10 * bf2f(b2[j]) + W11 * bf2f(b3[j]));
                    }
                } else if constexpr (META2) {
                    // NCHW deform: meta from LDS in scoped 8-tap batches
                    const int ci = (k0 >> 4) + bkc;
                    const float* img = Xb + (size_t)ci * HWc;
                    const int mb = bn2 * KPAD;
#pragma unroll
                    for (int jh = 0; jh < 2; ++jh) {
                        int pk[8]; unsigned wa[8], wb[8];
#pragma unroll
                        for (int j = 0; j < 8; ++j) pk[j] = MIb[mb + jh * 8 + j];
#pragma unroll
                        for (int j = 0; j < 8; ++j) {
                            uint2 ww = MWh[mb + jh * 8 + j];
                            wa[j] = ww.x; wb[j] = ww.y;
                        }
                        float c0[8], c1[8], c2[8], c3[8];
#pragma unroll
                        for (int j = 0; j < 8; ++j) {
                            int p = pk[j];
                            int base = p & 0xFFFFFF;
                            int dxs  = (p >> 24) & 1;
                            int dys  = ((p >> 25) & 1) ? W : 0;
                            c0[j] = img[base];
                            c1[j] = img[base + dxs];
                            c2[j] = img[base + dys];
                            c3[j] = img[base + dys + dxs];
                        }
#pragma unroll
                        for (int j = 0; j < 8; ++j) {
                            half2v w01 = __builtin_bit_cast(half2v, wa[j]);
                            half2v w23 = __builtin_bit_cast(half2v, wb[j]);
                            tmp[jh * 8 + j] = f2bf((float)w01[0] * c0[j] + (float)w01[1] * c1[j]
                                                 + (float)w23[0] * c2[j] + (float)w23[1] * c3[j]);
                        }
                    }
                } else if constexpr (M2P) {
                    // stage-1 deform, perm'd K: 4 slots share one r (3 planes + pad)
                    const int kbase = k0 + bkc * 16;
                    const int rbase = kbase >> 2;
#pragma unroll
                    for (int u = 0; u < 4; ++u) {
                        const int r = rbase + u;
                        float v0 = 0.f, v1 = 0.f, v2 = 0.f;
                        if (r < Kk) {
                            const int ky = r / KW, kx = r - ky * KW;
                            float offy = OMb[(size_t)(2 * r) * HOWO + gn2];
                            float offx = OMb[(size_t)(2 * r + 1) * HOWO + gn2];
                            float ml   = OMb[(size_t)(2 * Kk + r) * HOWO + gn2];
                            float mask = 1.f / (1.f + expf(-ml));
                            float ys = (float)(ho2 * STR - PAD + ky) + offy;
                            float xs = (float)(wo2 * STR - PAD + kx) + offx;
                            float y0f = floorf(ys), x0f = floorf(xs);
                            float dy = ys - y0f, dx = xs - x0f;
                            int y0 = (int)y0f, x0 = (int)x0f;
                            int yc0 = min(max(y0, 0), H - 1);
                            int yc1 = min(max(y0 + 1, 0), H - 1);
                            int xc0 = min(max(x0, 0), W - 1);
                            int xc1 = min(max(x0 + 1, 0), W - 1);
                            bool y0ok = (y0 >= 0) & (y0 < H), y1ok = (y0 + 1 >= 0) & (y0 + 1 < H);
                            bool x0ok = (x0 >= 0) & (x0 < W), x1ok = (x0 + 1 >= 0) & (x0 + 1 < W);
                            float w00 = (y0ok && x0ok) ? (1.f - dy) * (1.f - dx) * mask : 0.f;
                            float w01 = (y0ok && x1ok) ? (1.f - dy) * dx * mask : 0.f;
                            float w10 = (y1ok && x0ok) ? dy * (1.f - dx) * mask : 0.f;
                            float w11 = (y1ok && x1ok) ? dy * dx * mask : 0.f;
                            int base = yc0 * W + xc0;
                            int dxs  = xc1 - xc0;
                            int dys  = (yc1 - yc0) ? W : 0;
                            float cc[12];
#pragma unroll
                            for (int ci = 0; ci < 3; ++ci) {
                                const float* img = Xb + (size_t)ci * HWc;
                                cc[ci * 4 + 0] = img[base];
                                cc[ci * 4 + 1] = img[base + dxs];
                                cc[ci * 4 + 2] = img[base + dys];
                                cc[ci * 4 + 3] = img[base + dys + dxs];
                            }
                            v0 = w00 * cc[0] + w01 * cc[1] + w10 * cc[2]  + w11 * cc[3];
                            v1 = w00 * cc[4] + w01 * cc[5] + w10 * cc[6]  + w11 * cc[7];
                            v2 = w00 * cc[8] + w01 * cc[9] + w10 * cc[10] + w11 * cc[11];
                        }
                        tmp[u * 4 + 0] = f2bf(v0);
                        tmp[u * 4 + 1] = f2bf(v1);
                        tmp[u * 4 + 2] = f2bf(v2);
                        tmp[u * 4 + 3] = 0;
                    }
                } else if constexpr (M0R) {
                    const int ci = (k0 >> 4) + bkc;
                    const float* img = Xb + (size_t)ci * HWc;
                    float raw[16];
#pragma unroll
                    for (int j = 0; j < 16; ++j) raw[j] = img[rix[j] < 0 ? 0 : rix[j]];
#pragma unroll
                    for (int j = 0; j < 16; ++j) tmp[j] = rix[j] < 0 ? (ush)0 : f2bf(raw[j]);
                } else {
                    // NCHW MLUT: batched idx reads then unconditional clamped gathers
                    int idxs[16], cis[16];
#pragma unroll
                    for (int j = 0; j < 16; ++j) {
                        int gk = k0 + bkc * 16 + j;
                        int ci = (Kk == 16) ? (gk >> 4) : gk / Kk;
                        int r  = gk - ci * Kk;
                        int idx = MI0[bn2 * KPAD + r];
                        if (KGUARD && gk >= Ktot) idx = -1;
                        idxs[j] = idx; cis[j] = ci;
                    }
                    float raw[16];
#pragma unroll
                    for (int j = 0; j < 16; ++j)
                        raw[j] = Xb[(size_t)cis[j] * HWc + (idxs[j] < 0 ? 0 : idxs[j])];
#pragma unroll
                    for (int j = 0; j < 16; ++j)
                        tmp[j] = idxs[j] < 0 ? (ush)0 : f2bf(raw[j]);
                }
#pragma unroll
                for (int j = 0; j < 8; ++j) { s0[j] = (short)tmp[j]; s1[j] = (short)tmp[8 + j]; }
            }
            const int g0 = (bkc * 2)     ^ (bn2 & 7);
            const int g1 = (bkc * 2 + 1) ^ (bn2 & 7);
            *(short8*)&Bs[bn2][g0 * 8] = s0;
            *(short8*)&Bs[bn2][g1 * 8] = s1;
        }
        __syncthreads();

        // ---- MFMA: wave computes MT x 16(m) x 64(n), K=64
        {
            const int mrow = wave * 16 + l16;
#pragma unroll
            for (int kk = 0; kk < 2; ++kk) {
                const int kg = kk * 4 + quad;
                short8 a[MT];
#pragma unroll
                for (int s = 0; s < MT; ++s)
                    a[s] = *(const short8*)&As[s * 64 + mrow][((kg ^ (mrow & 7)) * 8)];
#pragma unroll
                for (int t = 0; t < 4; ++t) {
                    const int ncol = t * 16 + l16;
                    short8 b = *(const short8*)&Bs[ncol][((kg ^ (ncol & 7)) * 8)];
#pragma unroll
                    for (int s = 0; s < MT; ++s)
                        acc[s][t] = __builtin_amdgcn_mfma_f32_16x16x32_bf16(a[s], b, acc[s][t], 0, 0, 0);
                }
            }
        }
        __syncthreads();
    }

    // ---- epilogue
    if constexpr (ONHWC) {
        // LDS transpose -> coalesced NHWC store (M==64, full tile)
#pragma unroll
        for (int t = 0; t < 4; ++t) {
            int n = t * 16 + l16;
#pragma unroll
            for (int i = 0; i < 4; ++i) {
                int m = wave * 16 + quad * 4 + i;
                Ts[n * 64 + (m ^ ((n & 7) << 3))] = acc[0][t][i] + bias[m];
            }
        }
        __syncthreads();
        float* Outc = Out + ((size_t)z * HOWO + n0) * 64;
        for (int e = tid; e < 1024; e += 256) {
            int n = e >> 4, m4 = (e & 15) * 4;
            float4 v = *(float4*)&Ts[n * 64 + (m4 ^ ((n & 7) << 3))];
            *(float4*)(Outc + n * 64 + m4) = v;
        }
    } else {
#pragma unroll
        for (int s = 0; s < MT; ++s) {
#pragma unroll
            for (int t = 0; t < 4; ++t) {
                const int ng = n0 + t * 16 + l16;
#pragma unroll
                for (int i = 0; i < 4; ++i) {
                    int mg = my * (64 * MT) + s * 64 + wave * 16 + quad * 4 + i;
                    if (mg < M) {
                        float v = acc[s][t][i];
                        if constexpr (NKS == 1) v += bias[mg];
                        Outb[(size_t)mg * HOWO + ng] = v;
                    }
                }
            }
        }
    }
}

// Sum NP partial planes (stride PS) + bias -> out. One block per (z,m) row.
template<int NP>
__global__ __launch_bounds__(256) void reduce_bias_k(
    const float* __restrict__ P, size_t PS, const float* __restrict__ bias,
    float* __restrict__ out, int M, int HOWO)
{
    const int bc = blockIdx.x;
    const int m  = bc % M;
    const float b = bias[m];
    const size_t off = (size_t)bc * HOWO;
    for (int i = threadIdx.x * 4; i < HOWO; i += 1024) {
        float4 a = *(const float4*)(P + off + i);
#pragma unroll
        for (int p = 1; p < NP; ++p) {
            float4 c = *(const float4*)(P + (size_t)p * PS + off + i);
            a.x += c.x; a.y += c.y; a.z += c.z; a.w += c.w;
        }
        a.x += b; a.y += b; a.z += b; a.w += b;
        *(float4*)(out + off + i) = a;
    }
}

// NCHW instance norm (per (b,c) over HW); optional ReLU/dual/add-in. float4.
template<bool RELU, bool DUAL, bool ADDIN>
__global__ __launch_bounds__(256) void instnorm_k(
    const float* __restrict__ in, float* __restrict__ out,
    float* __restrict__ out2, int HW)
{
    const int bc = blockIdx.x;
    const float4* p4 = (const float4*)(in + (size_t)bc * HW);
    const int n4 = HW >> 2;
    float s = 0.f, ss = 0.f;
    for (int i = threadIdx.x; i < n4; i += 256) {
        float4 v = p4[i];
        s  += v.x + v.y + v.z + v.w;
        ss += v.x * v.x + v.y * v.y + v.z * v.z + v.w * v.w;
    }
    __shared__ float rs[256], rq[256];
    rs[threadIdx.x] = s; rq[threadIdx.x] = ss;
    __syncthreads();
    for (int o = 128; o > 0; o >>= 1) {
        if (threadIdx.x < o) { rs[threadIdx.x] += rs[threadIdx.x + o]; rq[threadIdx.x] += rq[threadIdx.x + o]; }
        __syncthreads();
    }
    float mean = rs[0] / (float)HW;
    float var  = rq[0] / (float)HW - mean * mean;
    float inv  = rsqrtf(var + 1e-5f);
    float4* q4  = (float4*)(out + (size_t)bc * HW);
    float4* q24 = DUAL ? (float4*)(out2 + (size_t)bc * HW) : nullptr;
    for (int i = threadIdx.x; i < n4; i += 256) {
        float4 v = p4[i];
        v.x = (v.x - mean) * inv; v.y = (v.y - mean) * inv;
        v.z = (v.z - mean) * inv; v.w = (v.w - mean) * inv;
        if (RELU) {
            v.x = fmaxf(v.x, 0.f); v.y = fmaxf(v.y, 0.f);
            v.z = fmaxf(v.z, 0.f); v.w = fmaxf(v.w, 0.f);
        }
        if (ADDIN) {
            float4 o = q4[i];
            o.x += v.x; o.y += v.y; o.z += v.z; o.w += v.w;
            q4[i] = o;
        } else {
            q4[i] = v;
            if (DUAL) q24[i] = v;
        }
    }
}

// NHWC instance-norm stats: per (z, chunk of 1024 hw) partial s/ss per channel.
__global__ __launch_bounds__(256) void in_stats_nhwc(
    const float* __restrict__ X, float2* __restrict__ P, int HW)
{
    const int z = blockIdx.x, chunk = blockIdx.y;
    const int tid = threadIdx.x;
    const int cg = tid & 15, seg = tid >> 4;
    const int c0 = cg * 4;
    float4 s4 = make_float4(0.f, 0.f, 0.f, 0.f);
    float4 q4 = make_float4(0.f, 0.f, 0.f, 0.f);
    const float* base = X + ((size_t)z * HW + chunk * 1024) * 64;
    for (int hw = seg; hw < 1024; hw += 16) {
        float4 v = *(const float4*)(base + (size_t)hw * 64 + c0);
        s4.x += v.x; s4.y += v.y; s4.z += v.z; s4.w += v.w;
        q4.x += v.x * v.x; q4.y += v.y * v.y; q4.z += v.z * v.z; q4.w += v.w * v.w;
    }
    __shared__ float4 rs[256], rq[256];
    rs[tid] = s4; rq[tid] = q4;
    __syncthreads();
    if (tid < 16) {
        float4 S = rs[tid], Q = rq[tid];
        for (int g = 1; g < 16; ++g) {
            float4 a = rs[g * 16 + tid], b = rq[g * 16 + tid];
            S.x += a.x; S.y += a.y; S.z += a.z; S.w += a.w;
            Q.x += b.x; Q.y += b.y; Q.z += b.z; Q.w += b.w;
        }
        float2* po = P + ((size_t)z * 16 + chunk) * 64 + tid * 4;
        po[0] = make_float2(S.x, Q.x);
        po[1] = make_float2(S.y, Q.y);
        po[2] = make_float2(S.z, Q.z);
        po[3] = make_float2(S.w, Q.w);
    }
}

// NHWC normalize + ReLU, fp32 in -> bf16 out. grid (Z, 64 chunks of 256 hw).
__global__ __launch_bounds__(256) void in_norm_nhwc_bf16(
    const float2* __restrict__ P, const float* __restrict__ X,
    ush* __restrict__ Y, int HW)
{
    const int z = blockIdx.x, chunk = blockIdx.y;
    const int tid = threadIdx.x;
    __shared__ float2 mi[64];
    if (tid < 64) {
        float s = 0.f, q = 0.f;
        for (int g = 0; g < 16; ++g) {
            float2 p = P[((size_t)z * 16 + g) * 64 + tid];
            s += p.x; q += p.y;
        }
        float mean = s / (float)HW;
        float var  = q / (float)HW - mean * mean;
        mi[tid] = make_float2(mean, rsqrtf(var + 1e-5f));
    }
    __syncthreads();
    const float* bi = X + ((size_t)z * HW + chunk * 256) * 64;
    ush* bo = Y + ((size_t)z * HW + chunk * 256) * 64;
    for (int e = tid; e < 4096; e += 256) {
        int c0 = (e & 15) * 4;
        float4 v = *(const float4*)(bi + (size_t)e * 4);
        float2 m0 = mi[c0], m1 = mi[c0 + 1], m2 = mi[c0 + 2], m3 = mi[c0 + 3];
        sh4 o;
        o[0] = (short)f2bf(fmaxf((v.x - m0.x) * m0.y, 0.f));
        o[1] = (short)f2bf(fmaxf((v.y - m1.x) * m1.y, 0.f));
        o[2] = (short)f2bf(fmaxf((v.z - m2.x) * m2.y, 0.f));
        o[3] = (short)f2bf(fmaxf((v.w - m3.x) * m3.y, 0.f));
        *(sh4*)(bo + (size_t)e * 4) = o;
    }
}

// Tiled NCHW fp32 [Z][C][HW] -> NHWC bf16 [Z][HW][C]. grid (HW/64, C/64, Z).
__global__ __launch_bounds__(256) void transpose_chw_hwc_bf16(
    const float* __restrict__ src, ush* __restrict__ dst, int C, int HW)
{
    __shared__ float T[64][65];
    const int z = blockIdx.z, cb = blockIdx.y * 64, hb = blockIdx.x * 64;
    const int tid = threadIdx.x;
    for (int e = tid; e < 1024; e += 256) {
        int c = e >> 4, h4 = (e & 15) * 4;
        float4 v = *(const float4*)(src + ((size_t)z * C + cb + c) * HW + hb + h4);
        T[c][h4] = v.x; T[c][h4 + 1] = v.y; T[c][h4 + 2] = v.z; T[c][h4 + 3] = v.w;
    }
    __syncthreads();
    for (int e = tid; e < 1024; e += 256) {
        int h = e >> 4, c4 = (e & 15) * 4;
        sh4 o;
        o[0] = (short)f2bf(T[c4][h]);     o[1] = (short)f2bf(T[c4 + 1][h]);
        o[2] = (short)f2bf(T[c4 + 2][h]); o[3] = (short)f2bf(T[c4 + 3][h]);
        *(sh4*)(dst + ((size_t)z * HW + hb + h) * C + cb + c4) = o;
    }
}

extern "C" void kernel_launch(void* const* d_in, const int* in_sizes, int n_in,
                              void* d_out, int out_size, void* d_ws, size_t ws_size,
                              hipStream_t stream)
{
    const float* x      = (const float*)d_in[0];
    const float* w_off1 = (const float*)d_in[1];
    const float* b_off1 = (const float*)d_in[2];
    const float* w1     = (const float*)d_in[3];
    const float* b1     = (const float*)d_in[4];
    const float* w_off2 = (const float*)d_in[5];
    const float* b_off2 = (const float*)d_in[6];
    const float* w2     = (const float*)d_in[7];
    const float* b2     = (const float*)d_in[8];
    const float* w_off3 = (const float*)d_in[9];
    const float* b_off3 = (const float*)d_in[10];
    const float* w3     = (const float*)d_in[11];
    const float* b3     = (const float*)d_in[12];
    const float* rwa[2] = {(const float*)d_in[13], (const float*)d_in[17]};
    const float* rba[2] = {(const float*)d_in[14], (const float*)d_in[18]};
    const float* rwb[2] = {(const float*)d_in[15], (const float*)d_in[19]};
    const float* rbb[2] = {(const float*)d_in[16], (const float*)d_in[20]};

    float* out   = (float*)d_out;
    float* h_out = out;                         // [16,256,32,32]
    float* skip2 = out + 4194304;               // [16,128,64,64]
    float* skip3 = out + 4194304 + 8388608;     // [16,256,32,32]

    // workspace (floats), time-multiplexed:
    //  h1 region [0..16.77M):
    //    h1 fp32 NHWC (stage 1, dead after in_norm) |
    //    om2 at +8.39M (stage 2) | skip2t bf16 at +0 (stage 3) |
    //    kp at +8.39M (stage 3 & residuals)
    //  pool [16.77M..28.08M):
    //    om1 [0..9.63M) stage 1 | h1b bf16 [0..8.39M) stage 2 |
    //    om3 [8.39M..9.18M) stage 3 | y1 [0..4.19M), y2 [4.19M..8.39M) residuals |
    //    wprep [9.63M..11.27M) | Pst [11.27M..11.31M)
    float*  wsf    = (float*)d_ws;
    float*  h1     = wsf;
    float*  om2    = wsf + 8388608;
    ush*    skip2t = (ush*)wsf;
    float*  kp     = wsf + 8388608;
    float*  pool   = wsf + 16777216;
    float*  om1    = pool;
    ush*    h1b    = (ush*)pool;
    float*  om3    = pool + 8388608;
    float*  y1     = pool;
    float*  y2     = pool + 4194304;
    ush*    wprep  = (ush*)(pool + 9633792);
    float2* Pst    = (float2*)(pool + 11272192);

    // ---- Weight prep
    {
        PrepAll pd;
        const float* srcs[NWT] = {w_off1, w1, w_off2, w2, w_off3, w3,
                                  rwa[0], rwb[0], rwa[1], rwb[1]};
        const int Ms  [NWT] = {147, 64, 48, 128, 48, 256, 256, 256, 256, 256};
        const int Kts [NWT] = {147, 196, 1024, 1024, 2048, 2048, 2304, 2304, 2304, 2304};
        const int KTs [NWT] = {192, 256, 1024, 1024, 2048, 2048, 2304, 2304, 2304, 2304};
        const int Mbs [NWT] = {128, 64, 64, 128, 64, 128, 128, 128, 128, 128};
        const int sKs [NWT] = {147, 147, 1024, 1024, 2048, 2048, 2304, 2304, 2304, 2304};
        const int prm [NWT] = {0, 1, 2, 2, 2, 2, 0, 0, 0, 0};
        const int cns [NWT] = {3, 3, 64, 64, 128, 128, 256, 256, 256, 256};
        int sg = 0;
        pd.startG[0] = 0;
        for (int i = 0; i < NWT; ++i) {
            pd.src[i] = srcs[i];
            pd.M[i] = Ms[i]; pd.Ktot[i] = Kts[i]; pd.KT[i] = KTs[i];
            pd.Mblk[i] = Mbs[i]; pd.srcK[i] = sKs[i]; pd.perm[i] = prm[i];
            pd.cin[i] = cns[i];
            pd.dstOff[i] = (unsigned)sg * 8u;
            int mb = (Ms[i] + Mbs[i] - 1) / Mbs[i];
            sg += mb * (KTs[i] >> 6) * Mbs[i] * 8;
            pd.startG[i + 1] = sg;
        }
        prep_all_k<<<dim3((sg + 255) / 256), 256, 0, stream>>>(pd, wprep);
    }
    const ush* pw_off1 = wprep + 0;
    const ush* pw1     = wprep + 49152;
    const ush* pw_off2 = wprep + 65536;
    const ush* pw2     = wprep + 131072;
    const ush* pw_off3 = wprep + 262144;
    const ush* pw3     = wprep + 393216;
    const ush* prwa[2] = {wprep + 917504,  wprep + 2097152};
    const ush* prwb[2] = {wprep + 1507328, wprep + 2686976};

    // ---- Stage 1: 7x7 s1 p3, 3 -> 64ch @128x128; h1 written NHWC fp32
    for (int c = 0; c < 4; ++c) {
        const float* xc = x + (size_t)c * 4 * 3 * 16384;
        conv_mfma<3,7,7,1,3,128,128,128,128,0,2><<<dim3(256, 2, 4), 256, 0, stream>>>(
            pw_off1, xc, nullptr, b_off1, om1, 147);
        conv_mfma<3,7,7,1,3,128,128,128,128,2,1,1,1,0,1><<<dim3(256, 1, 4), 256, 0, stream>>>(
            pw1, xc, om1, b1, h1 + (size_t)c * 4 * 16384 * 64, 64);
    }
    in_stats_nhwc<<<dim3(16, 16), 256, 0, stream>>>(h1, Pst, 16384);
    in_norm_nhwc_bf16<<<dim3(16, 64), 256, 0, stream>>>(Pst, h1, h1b, 16384);

    // ---- Stage 2: 4x4 s2 p1, 64 -> 128ch @64x64 (NHWC bf16 input, z-swizzle)
    conv_mfma<64,4,4,2,1,128,128,64,64,0,1,0,1,1,0,1><<<dim3(64, 1, 16), 256, 0, stream>>>(
        pw_off2, (const float*)h1b, nullptr, b_off2, om2, 48);
    conv_mfma<64,4,4,2,1,128,128,64,64,2,2,0,1,1,0,1><<<dim3(64, 1, 16), 256, 0, stream>>>(
        pw2, (const float*)h1b, om2, b2, skip2, 128);
    instnorm_k<true,false,false><<<16 * 128, 256, 0, stream>>>(skip2, skip2, nullptr, 4096);
    transpose_chw_hwc_bf16<<<dim3(64, 2, 16), 256, 0, stream>>>(skip2, skip2t, 128, 4096);

    // ---- Stage 3: 4x4 s2 p1, 128 -> 256ch @32x32 (NHWC bf16, K-split, z-swz)
    conv_mfma<128,4,4,2,1,64,64,32,32,0,1,0,4,1,0,1><<<dim3(16, 4, 16), 256, 0, stream>>>(
        pw_off3, (const float*)skip2t, nullptr, b_off3, kp, 48);
    reduce_bias_k<4><<<16 * 48, 256, 0, stream>>>(kp, 786432, b_off3, om3, 48, 1024);
    conv_mfma<128,4,4,2,1,64,64,32,32,2,2,0,2,1,0,1><<<dim3(16, 4, 16), 256, 0, stream>>>(
        pw3, (const float*)skip2t, om3, b3, kp, 256);
    reduce_bias_k<2><<<16 * 256, 256, 0, stream>>>(kp, 4194304, b3, skip3, 256, 1024);
    instnorm_k<true,true,false><<<16 * 256, 256, 0, stream>>>(skip3, skip3, h_out, 1024);

    // ---- Residual blocks: reflect 3x3, 256ch @32x32 (NCHW, K-split 2, z-swz)
    for (int r = 0; r < 2; ++r) {
        conv_mfma<256,3,3,1,1,32,32,32,32,1,2,0,2,0,0,1><<<dim3(16, 4, 16), 256, 0, stream>>>(
            prwa[r], h_out, nullptr, rba[r], kp, 256);
        reduce_bias_k<2><<<16 * 256, 256, 0, stream>>>(kp, 4194304, rba[r], y1, 256, 1024);
        instnorm_k<true,false,false><<<16 * 256, 256, 0, stream>>>(y1, y1, nullptr, 1024);
        conv_mfma<256,3,3,1,1,32,32,32,32,1,2,0,2,0,0,1><<<dim3(16, 4, 16), 256, 0, stream>>>(
            prwb[r], y1, nullptr, rbb[r], kp, 256);
        reduce_bias_k<2><<<16 * 256, 256, 0, stream>>>(kp, 4194304, rbb[r], y2, 256, 1024);
        instnorm_k<false,false,true><<<16 * 256, 256, 0, stream>>>(y2, h_out, nullptr, 1024);
    }
}